// Round 1
// baseline (502.093 us; speedup 1.0000x reference)
//
#include <hip/hip_runtime.h>

#define F0 128
#define F1 64
#define F2 32

// ---------------- degree / norm ----------------
__global__ void deg_count(const int* __restrict__ dst, int* __restrict__ deg, int E) {
    int e = blockIdx.x * blockDim.x + threadIdx.x;
    if (e < E) atomicAdd(&deg[dst[e]], 1);
}

__global__ void compute_dinv(const int* __restrict__ deg, float* __restrict__ dinv, int N) {
    int v = blockIdx.x * blockDim.x + threadIdx.x;
    if (v < N) dinv[v] = rsqrtf((float)(deg[v] + 1));  // +1 self-loop; always > 0
}

// ---------------- GEMM1: xw1 = x @ W1  [N,128]x[128,64] ----------------
__global__ void gemm1(const float* __restrict__ x, const float* __restrict__ W1,
                      float* __restrict__ xw1, int N) {
    __shared__ float sW[F0 * F1];   // 32 KB
    __shared__ float sx[4 * F0];    // 2 KB
    int tid = threadIdx.x;
    for (int i = tid; i < F0 * F1; i += 256) sW[i] = W1[i];
    int rowL = tid >> 6, col = tid & 63;
    int row = blockIdx.x * 4 + rowL;
    if (row < N) {
        sx[rowL * F0 + col]      = x[(size_t)row * F0 + col];
        sx[rowL * F0 + col + 64] = x[(size_t)row * F0 + col + 64];
    }
    __syncthreads();
    if (row >= N) return;
    float acc = 0.f;
    #pragma unroll
    for (int k = 0; k < F0; ++k) acc += sx[rowL * F0 + k] * sW[k * F1 + col];
    xw1[(size_t)row * F1 + col] = acc;
}

// ---------------- edge scatter, 64 cols: one (edge,col) per thread ----------------
__global__ void scatter1(const int* __restrict__ src, const int* __restrict__ dst,
                         const float* __restrict__ dinv, const float* __restrict__ xw1,
                         float* __restrict__ agg, int E) {
    int t = blockIdx.x * 256 + threadIdx.x;
    int e = t >> 6, c = t & 63;
    if (e < E) {
        int s = src[e], d = dst[e];
        float w = dinv[s] * dinv[d];
        atomicAdd(&agg[(size_t)d * F1 + c], xw1[(size_t)s * F1 + c] * w);
    }
}

// ---------------- self-loop + bias + ReLU, 64 cols ----------------
__global__ void selfrelu1(float* __restrict__ h1, const float* __restrict__ xw1,
                          const float* __restrict__ dinv, const float* __restrict__ b1, int N) {
    int t = blockIdx.x * 256 + threadIdx.x;
    int v = t >> 6, c = t & 63;
    if (v < N) {
        float di = dinv[v];
        float val = h1[t] + di * di * xw1[t] + b1[c];
        h1[t] = val > 0.f ? val : 0.f;
    }
}

// ---------------- GEMM2: xw2 = h1 @ W2  [N,64]x[64,32] ----------------
__global__ void gemm2(const float* __restrict__ h1, const float* __restrict__ W2,
                      float* __restrict__ xw2, int N) {
    __shared__ float sW[F1 * F2];  // 8 KB
    __shared__ float sx[8 * F1];   // 2 KB
    int tid = threadIdx.x;
    for (int i = tid; i < F1 * F2; i += 256) sW[i] = W2[i];
    int rowL = tid >> 5, col = tid & 31;
    int row = blockIdx.x * 8 + rowL;
    if (row < N) {
        sx[rowL * F1 + col]      = h1[(size_t)row * F1 + col];
        sx[rowL * F1 + col + 32] = h1[(size_t)row * F1 + col + 32];
    }
    __syncthreads();
    if (row >= N) return;
    float acc = 0.f;
    #pragma unroll
    for (int k = 0; k < F1; ++k) acc += sx[rowL * F1 + k] * sW[k * F2 + col];
    xw2[(size_t)row * F2 + col] = acc;
}

// ---------------- edge scatter, 32 cols ----------------
__global__ void scatter2(const int* __restrict__ src, const int* __restrict__ dst,
                         const float* __restrict__ dinv, const float* __restrict__ xw2,
                         float* __restrict__ agg, int E) {
    int t = blockIdx.x * 256 + threadIdx.x;
    int e = t >> 5, c = t & 31;
    if (e < E) {
        int s = src[e], d = dst[e];
        float w = dinv[s] * dinv[d];
        atomicAdd(&agg[(size_t)d * F2 + c], xw2[(size_t)s * F2 + c] * w);
    }
}

__global__ void selfrelu2(float* __restrict__ h2, const float* __restrict__ xw2,
                          const float* __restrict__ dinv, const float* __restrict__ b2, int N) {
    int t = blockIdx.x * 256 + threadIdx.x;
    int v = t >> 5, c = t & 31;
    if (v < N) {
        float di = dinv[v];
        float val = h2[t] + di * di * xw2[t] + b2[c];
        h2[t] = val > 0.f ? val : 0.f;
    }
}

// ---------------- GEMM3: out = h2 @ Wl + bl  [N,32]x[32,128] ----------------
__global__ void gemm3(const float* __restrict__ h2, const float* __restrict__ Wl,
                      const float* __restrict__ bl, float* __restrict__ out, int N) {
    __shared__ float sW[F2 * F0];  // 16 KB
    __shared__ float sx[2 * F2];
    __shared__ float sb[F0];
    int tid = threadIdx.x;
    for (int i = tid; i < F2 * F0; i += 256) sW[i] = Wl[i];
    if (tid < F0) sb[tid] = bl[tid];
    int rowL = tid >> 7, col = tid & 127;
    int row = blockIdx.x * 2 + rowL;
    if (tid < 2 * F2) {
        int r = blockIdx.x * 2 + (tid >> 5);
        if (r < N) sx[tid] = h2[(size_t)r * F2 + (tid & 31)];
    }
    __syncthreads();
    if (row >= N) return;
    float acc = sb[col];
    #pragma unroll
    for (int k = 0; k < F2; ++k) acc += sx[rowL * F2 + k] * sW[k * F0 + col];
    out[(size_t)row * F0 + col] = acc;
}

extern "C" void kernel_launch(void* const* d_in, const int* in_sizes, int n_in,
                              void* d_out, int out_size, void* d_ws, size_t ws_size,
                              hipStream_t stream) {
    const float* x  = (const float*)d_in[0];
    const int*   ei = (const int*)d_in[1];
    const float* W1 = (const float*)d_in[2];
    const float* b1 = (const float*)d_in[3];
    const float* W2 = (const float*)d_in[4];
    const float* b2 = (const float*)d_in[5];
    const float* Wl = (const float*)d_in[6];
    const float* bl = (const float*)d_in[7];
    float* out = (float*)d_out;

    const int N = in_sizes[0] / F0;   // 50000
    const int E = in_sizes[1] / 2;    // 800000
    const int* src = ei;
    const int* dst = ei + E;

    char* ws = (char*)d_ws;
    size_t off = 0;
    auto alloc = [&](size_t bytes) {
        void* p = ws + off;
        off += (bytes + 255) & ~(size_t)255;
        return p;
    };
    int*   deg  = (int*)alloc((size_t)N * 4);
    float* dinv = (float*)alloc((size_t)N * 4);
    float* xw1  = (float*)alloc((size_t)N * F1 * 4);
    float* h1   = (float*)alloc((size_t)N * F1 * 4);
    float* xw2  = (float*)alloc((size_t)N * F2 * 4);
    float* h2   = (float*)alloc((size_t)N * F2 * 4);

    hipMemsetAsync(deg, 0, (size_t)N * 4, stream);
    hipMemsetAsync(h1, 0, (size_t)N * F1 * 4, stream);
    hipMemsetAsync(h2, 0, (size_t)N * F2 * 4, stream);

    deg_count<<<(E + 255) / 256, 256, 0, stream>>>(dst, deg, E);
    compute_dinv<<<(N + 255) / 256, 256, 0, stream>>>(deg, dinv, N);

    gemm1<<<(N + 3) / 4, 256, 0, stream>>>(x, W1, xw1, N);
    {
        long long work = (long long)E * F1;
        scatter1<<<(int)((work + 255) / 256), 256, 0, stream>>>(src, dst, dinv, xw1, h1, E);
    }
    selfrelu1<<<(N * F1 + 255) / 256, 256, 0, stream>>>(h1, xw1, dinv, b1, N);

    gemm2<<<(N + 7) / 8, 256, 0, stream>>>(h1, W2, xw2, N);
    {
        long long work = (long long)E * F2;
        scatter2<<<(int)((work + 255) / 256), 256, 0, stream>>>(src, dst, dinv, xw2, h2, E);
    }
    selfrelu2<<<(N * F2 + 255) / 256, 256, 0, stream>>>(h2, xw2, dinv, b2, N);

    gemm3<<<(N + 1) / 2, 256, 0, stream>>>(h2, Wl, bl, out, N);
}

// Round 2
// 370.992 us; speedup vs baseline: 1.3534x; 1.3534x over previous
//
#include <hip/hip_runtime.h>

#define F0 128
#define F1 64
#define F2 32

// ---------------- degree / norm ----------------
__global__ void deg_count(const int* __restrict__ dst, int* __restrict__ deg, int E) {
    int e = blockIdx.x * blockDim.x + threadIdx.x;
    if (e < E) atomicAdd(&deg[dst[e]], 1);
}

__global__ void compute_dinv(const int* __restrict__ deg, float* __restrict__ dinv, int N) {
    int v = blockIdx.x * blockDim.x + threadIdx.x;
    if (v < N) dinv[v] = rsqrtf((float)(deg[v] + 1));  // +1 self-loop; always > 0
}

// ---------------- exclusive scan of deg -> rowptr (3 kernels) ----------------
__global__ void scan1(const int* __restrict__ deg, int* __restrict__ rowptr,
                      int* __restrict__ bsum, int N) {
    __shared__ int s[256];
    int i = blockIdx.x * 256 + threadIdx.x;
    int v = (i < N) ? deg[i] : 0;
    s[threadIdx.x] = v;
    __syncthreads();
    for (int off = 1; off < 256; off <<= 1) {
        int t = 0;
        if (threadIdx.x >= off) t = s[threadIdx.x - off];
        __syncthreads();
        if (threadIdx.x >= off) s[threadIdx.x] += t;
        __syncthreads();
    }
    if (i < N) rowptr[i] = s[threadIdx.x] - v;  // exclusive
    if (threadIdx.x == 255) bsum[blockIdx.x] = s[255];
}

__global__ void scan2(int* __restrict__ bsum, int* __restrict__ boff, int nb) {
    __shared__ int s[256];
    int v = (threadIdx.x < nb) ? bsum[threadIdx.x] : 0;
    s[threadIdx.x] = v;
    __syncthreads();
    for (int off = 1; off < 256; off <<= 1) {
        int t = 0;
        if (threadIdx.x >= off) t = s[threadIdx.x - off];
        __syncthreads();
        if (threadIdx.x >= off) s[threadIdx.x] += t;
        __syncthreads();
    }
    if (threadIdx.x < nb) boff[threadIdx.x] = s[threadIdx.x] - v;  // exclusive
}

__global__ void scan3(int* __restrict__ rowptr, const int* __restrict__ boff, int N) {
    int i = blockIdx.x * 256 + threadIdx.x;
    if (i < N) rowptr[i] += boff[blockIdx.x];
}

// ---------------- bucket edges into CSR (by dst), store {src, dinv[src]} ----------------
__global__ void bucket(const int* __restrict__ src, const int* __restrict__ dst,
                       const int* __restrict__ rowptr, int* __restrict__ cursor,
                       const float* __restrict__ dinv, int2* __restrict__ csr, int E) {
    int e = blockIdx.x * 256 + threadIdx.x;
    if (e < E) {
        int d = dst[e], s = src[e];
        int pos = rowptr[d] + atomicAdd(&cursor[d], 1);
        csr[pos] = make_int2(s, __float_as_int(dinv[s]));
    }
}

// ---------------- GEMM1: xw1 = x @ W1  [N,128]x[128,64] ----------------
__global__ void gemm1(const float* __restrict__ x, const float* __restrict__ W1,
                      float* __restrict__ xw1, int N) {
    __shared__ float sW[F0 * F1];   // 32 KB
    __shared__ float sx[4 * F0];    // 2 KB
    int tid = threadIdx.x;
    for (int i = tid; i < F0 * F1; i += 256) sW[i] = W1[i];
    int rowL = tid >> 6, col = tid & 63;
    int row = blockIdx.x * 4 + rowL;
    if (row < N) {
        sx[rowL * F0 + col]      = x[(size_t)row * F0 + col];
        sx[rowL * F0 + col + 64] = x[(size_t)row * F0 + col + 64];
    }
    __syncthreads();
    if (row >= N) return;
    float acc = 0.f;
    #pragma unroll
    for (int k = 0; k < F0; ++k) acc += sx[rowL * F0 + k] * sW[k * F1 + col];
    xw1[(size_t)row * F1 + col] = acc;
}

// ---------------- gather1: one wave per node, lane = col (64), fused self-loop+bias+ReLU ----
__global__ void gather1(const int2* __restrict__ csr, const int* __restrict__ rowptr,
                        const int* __restrict__ deg, const float* __restrict__ dinv,
                        const float* __restrict__ xw1, const float* __restrict__ b1,
                        float* __restrict__ h1, int N) {
    int node = (blockIdx.x * 256 + threadIdx.x) >> 6;
    int lane = threadIdx.x & 63;
    if (node >= N) return;
    int start = rowptr[node], cnt = deg[node];
    float dd = dinv[node];
    float acc = 0.f;
    int j = start, end = start + cnt;
    for (; j + 1 < end; j += 2) {
        int2 e0 = csr[j];
        int2 e1 = csr[j + 1];
        float w0 = __int_as_float(e0.y) * dd;
        float w1 = __int_as_float(e1.y) * dd;
        acc += xw1[(size_t)e0.x * F1 + lane] * w0;
        acc += xw1[(size_t)e1.x * F1 + lane] * w1;
    }
    if (j < end) {
        int2 e0 = csr[j];
        acc += xw1[(size_t)e0.x * F1 + lane] * (__int_as_float(e0.y) * dd);
    }
    float v = acc + dd * dd * xw1[(size_t)node * F1 + lane] + b1[lane];
    h1[(size_t)node * F1 + lane] = fmaxf(v, 0.f);
}

// ---------------- GEMM2: xw2 = h1 @ W2  [N,64]x[64,32] ----------------
__global__ void gemm2(const float* __restrict__ h1, const float* __restrict__ W2,
                      float* __restrict__ xw2, int N) {
    __shared__ float sW[F1 * F2];  // 8 KB
    __shared__ float sx[8 * F1];   // 2 KB
    int tid = threadIdx.x;
    for (int i = tid; i < F1 * F2; i += 256) sW[i] = W2[i];
    int rowL = tid >> 5, col = tid & 31;
    int row = blockIdx.x * 8 + rowL;
    if (row < N) {
        sx[rowL * F1 + col]      = h1[(size_t)row * F1 + col];
        sx[rowL * F1 + col + 32] = h1[(size_t)row * F1 + col + 32];
    }
    __syncthreads();
    if (row >= N) return;
    float acc = 0.f;
    #pragma unroll
    for (int k = 0; k < F1; ++k) acc += sx[rowL * F1 + k] * sW[k * F2 + col];
    xw2[(size_t)row * F2 + col] = acc;
}

// ---------------- gather2: one wave per node, 32 cols, 2 edges/iter across wave halves ----
__global__ void gather2(const int2* __restrict__ csr, const int* __restrict__ rowptr,
                        const int* __restrict__ deg, const float* __restrict__ dinv,
                        const float* __restrict__ xw2, const float* __restrict__ b2,
                        float* __restrict__ h2, int N) {
    int node = (blockIdx.x * 256 + threadIdx.x) >> 6;
    int lane = threadIdx.x & 63;
    int c = lane & 31, half = lane >> 5;
    if (node >= N) return;
    int start = rowptr[node], cnt = deg[node];
    float dd = dinv[node];
    float acc = 0.f;
    for (int j = start + half; j < start + cnt; j += 2) {
        int2 ew = csr[j];
        acc += xw2[(size_t)ew.x * F2 + c] * (__int_as_float(ew.y) * dd);
    }
    acc += __shfl_down(acc, 32, 64);  // combine the two halves
    if (half == 0) {
        float v = acc + dd * dd * xw2[(size_t)node * F2 + c] + b2[c];
        h2[(size_t)node * F2 + c] = fmaxf(v, 0.f);
    }
}

// ---------------- GEMM3: out = h2 @ Wl + bl  [N,32]x[32,128] ----------------
__global__ void gemm3(const float* __restrict__ h2, const float* __restrict__ Wl,
                      const float* __restrict__ bl, float* __restrict__ out, int N) {
    __shared__ float sW[F2 * F0];  // 16 KB
    __shared__ float sx[2 * F2];
    __shared__ float sb[F0];
    int tid = threadIdx.x;
    for (int i = tid; i < F2 * F0; i += 256) sW[i] = Wl[i];
    if (tid < F0) sb[tid] = bl[tid];
    int rowL = tid >> 7, col = tid & 127;
    int row = blockIdx.x * 2 + rowL;
    if (tid < 2 * F2) {
        int r = blockIdx.x * 2 + (tid >> 5);
        if (r < N) sx[tid] = h2[(size_t)r * F2 + (tid & 31)];
    }
    __syncthreads();
    if (row >= N) return;
    float acc = sb[col];
    #pragma unroll
    for (int k = 0; k < F2; ++k) acc += sx[rowL * F2 + k] * sW[k * F0 + col];
    out[(size_t)row * F0 + col] = acc;
}

extern "C" void kernel_launch(void* const* d_in, const int* in_sizes, int n_in,
                              void* d_out, int out_size, void* d_ws, size_t ws_size,
                              hipStream_t stream) {
    const float* x  = (const float*)d_in[0];
    const int*   ei = (const int*)d_in[1];
    const float* W1 = (const float*)d_in[2];
    const float* b1 = (const float*)d_in[3];
    const float* W2 = (const float*)d_in[4];
    const float* b2 = (const float*)d_in[5];
    const float* Wl = (const float*)d_in[6];
    const float* bl = (const float*)d_in[7];
    float* out = (float*)d_out;

    const int N = in_sizes[0] / F0;   // 50000
    const int E = in_sizes[1] / 2;    // 800000
    const int* src = ei;
    const int* dst = ei + E;
    const int NB = (N + 255) / 256;   // scan blocks (196)

    char* ws = (char*)d_ws;
    size_t off = 0;
    auto alloc = [&](size_t bytes) {
        void* p = ws + off;
        off += (bytes + 255) & ~(size_t)255;
        return p;
    };
    int*   deg    = (int*)alloc((size_t)N * 4);
    float* dinv   = (float*)alloc((size_t)N * 4);
    int*   rowptr = (int*)alloc((size_t)N * 4);
    int*   cursor = (int*)alloc((size_t)N * 4);
    int*   bsum   = (int*)alloc((size_t)NB * 4);
    int*   boff   = (int*)alloc((size_t)NB * 4);
    int2*  csr    = (int2*)alloc((size_t)E * 8);
    float* xw1    = (float*)alloc((size_t)N * F1 * 4);   // also reused for xw2
    float* h1     = (float*)alloc((size_t)N * F1 * 4);   // also reused for h2
    float* xw2    = xw1;   // xw1 dead after gather1
    float* h2     = h1;    // h1 dead after gemm2

    hipMemsetAsync(deg, 0, (size_t)N * 4, stream);
    hipMemsetAsync(cursor, 0, (size_t)N * 4, stream);

    deg_count<<<(E + 255) / 256, 256, 0, stream>>>(dst, deg, E);
    compute_dinv<<<NB, 256, 0, stream>>>(deg, dinv, N);
    scan1<<<NB, 256, 0, stream>>>(deg, rowptr, bsum, N);
    scan2<<<1, 256, 0, stream>>>(bsum, boff, NB);
    scan3<<<NB, 256, 0, stream>>>(rowptr, boff, N);
    bucket<<<(E + 255) / 256, 256, 0, stream>>>(src, dst, rowptr, cursor, dinv, csr, E);

    gemm1<<<(N + 3) / 4, 256, 0, stream>>>(x, W1, xw1, N);
    gather1<<<(N + 3) / 4, 256, 0, stream>>>(csr, rowptr, deg, dinv, xw1, b1, h1, N);

    gemm2<<<(N + 7) / 8, 256, 0, stream>>>(h1, W2, xw2, N);
    gather2<<<(N + 3) / 4, 256, 0, stream>>>(csr, rowptr, deg, dinv, xw2, b2, h2, N);

    gemm3<<<(N + 1) / 2, 256, 0, stream>>>(h2, Wl, bl, out, N);
}